// Round 7
// baseline (189.406 us; speedup 1.0000x reference)
//
#include <hip/hip_runtime.h>
#include <math.h>

// Depth collapses to d=0 (x[:, :, 0:1] slicing): conv1d -> w[3]*xi+b,
// scan at d=0 -> hs[0]=BX[0] (A_log unused), y = xi*(delta*sum(B*C)+D).
//
// Round-7: 4 dispatches (conv0, ssm0, conv1, ssm1). prep_k removed:
//  - conv_k self-stages its weights: fp32 ipw rows read coalesced
//    (contiguous per-output 108-float runs), converted bf16 in-register,
//    packed to LDS [o'][c][10] (row stride 244B: gcd(61,32)=1 -> 2-way
//    free bank access). Same bflo/bfhi unpack as the verified wQb path.
//    Barriers stay at 2 (weight staging shares the hs-staging phase).
//  - wpT (ssm's transposed out_proj) is written by the conv0 DISPATCH
//    (48 elems/block prologue); consumed by ssm0/ssm1 in later
//    dispatches -> ordering by stream, no fences (round-1/5 lesson).
//  - og2-collapsed conv structure (round-6, verified 154.5us) kept;
//    ssmproj_k byte-identical to round-6.
#define NB   2
#define CM   96      // D_MODEL
#define CI   192     // D_INNER
#define CO   384     // 2*D_INNER
#define HP   24
#define WP   24
#define PX   576
#define DTR  6
#define NDBC 38
#define CSPLIT 8
#define CCH  12      // input channels per conv chunk (96/CSPLIT)
#define IPW_L (CO*CM*9)   // 331776 floats per layer of in_proj
#define WPT_L (CI*CM)     // 18432

__device__ __forceinline__ float siluf(float x){ return x / (1.f + expf(-x)); }
__device__ __forceinline__ float softplusf(float x){ return x > 20.f ? x : log1pf(expf(x)); }
__device__ __forceinline__ unsigned short f2bf(float f){
    unsigned u = __float_as_uint(f);
    return (unsigned short)((u + 0x7fffu + ((u >> 16) & 1u)) >> 16);
}
__device__ __forceinline__ float bflo(unsigned u){ return __uint_as_float(u << 16); }
__device__ __forceinline__ float bfhi(unsigned u){ return __uint_as_float(u & 0xffff0000u); }

// ---- conv: fused rmsnorm + 3x3 conv (pad 1), self-staged bf16 weights,
// fp32 accum. grid (NB*HP, 2, CSPLIT) = 768 blocks, block 256 (4 waves x
// 6-px strips). Each block computes 3 o-chunks of 64 (c outer, oc inner
// so hs LDS reads amortize 3x). acc layout: [cs][n][px][o]
__global__ __launch_bounds__(256) void conv_k(
    const float* __restrict__ x, long nStr, long cStr,
    const float* __restrict__ nw,
    const float* __restrict__ ipw,      // layer base: [o][c][9] fp32
    float* __restrict__ acc,
    const float* __restrict__ opw,      // full (2,96,192) or null
    float* __restrict__ wpT)            // full 2*WPT_L or null
{
    __shared__ unsigned short wu[192*122];  // bf16 taps [o'][c][10-pad] = 46848 B
    __shared__ float hs[CCH][3][28];        // every (c,j) row base 16B-aligned
    __shared__ float scl[CCH][3];
    int bx  = blockIdx.x;
    int og2 = blockIdx.y;              // 0..1 -> outputs og2*192 .. +192
    int cs  = blockIdx.z;
    int n  = bx / HP, hh = bx % HP;
    int tid = threadIdx.x;
    int c0 = cs*CCH;

    // ---- wpT prologue (conv0 only): 48 elements per block, consumed by
    // the LATER ssm dispatches (stream-ordered, no fence needed).
    if (opw != nullptr && tid < 48){
        int lin = bx + (NB*HP)*(og2 + 2*cs);
        int j = lin*48 + tid;
        int l = j / WPT_L, r = j % WPT_L;
        int c = r / CM, m = r % CM;
        wpT[l*WPT_L + c*CM + m] = opw[(long)(l*CM + m)*CI + c];
    }

    if (tid < CCH*3){
        int c = tid/3, j = tid%3;
        int row = hh + j - 1;
        float s = 0.f;
        if (row >= 0 && row < HP){
            const float4* xp4 = (const float4*)(x + (long)n*nStr + (long)(c0+c)*cStr + row*WP);
            #pragma unroll
            for (int w4 = 0; w4 < WP/4; w4++){
                float4 v = xp4[w4];
                s += v.x*v.x + v.y*v.y + v.z*v.z + v.w*v.w;
            }
            s = rsqrtf(s*(1.0f/WP) + 1e-5f) * nw[c0+c];
        }
        scl[c][j] = s;
    }
    __syncthreads();

    // ---- stage hs (normalized input halo rows)
    for (int idx = tid; idx < CCH*3*28; idx += 256){
        int c = idx/84; int rem = idx%84; int j = rem/28; int wc = rem%28;
        int row = hh + j - 1;
        float v = 0.f;
        if (row >= 0 && row < HP && wc >= 1 && wc <= WP)
            v = x[(long)n*nStr + (long)(c0+c)*cStr + row*WP + (wc-1)] * scl[c][j];
        hs[c][j][wc] = v;
    }

    // ---- stage weights: 192 outputs x 108 taps, coalesced fp32 reads,
    // bf16 pack into [o'][c*10 + k] (row stride 122 ush = 244 B).
    {
        const float* wsrc = ipw + (long)og2*192*(CM*9) + cs*(CCH*9);
        int o2 = tid / 108, t = tid - o2*108;
        for (int li = tid; li < 192*108; li += 256){
            float v = wsrc[(long)o2*(CM*9) + t];
            wu[o2*122 + (t/9)*10 + (t%9)] = f2bf(v);
            // advance (o2,t) by 256 = 2*108 + 40 without division
            o2 += 2; t += 40;
            if (t >= 108){ t -= 108; o2++; }
        }
    }
    __syncthreads();

    int ol = tid & 63;
    int obase = og2*192 + ol;          // + oc*64, oc in 0..2
    int x0 = (tid >> 6) * 6;           // even -> 8B-aligned float2 loads
    float a0[3][6] = {{0,0,0,0,0,0},{0,0,0,0,0,0},{0,0,0,0,0,0}};
    const unsigned* wu32 = (const unsigned*)wu;

    for (int c = 0; c < CCH; c++){
        float r0v[8], r1v[8], r2v[8];
        #pragma unroll
        for (int i = 0; i < 4; i++){
            float2 p0 = *(const float2*)(&hs[c][0][x0] + 2*i);
            float2 p1 = *(const float2*)(&hs[c][1][x0] + 2*i);
            float2 p2 = *(const float2*)(&hs[c][2][x0] + 2*i);
            r0v[2*i] = p0.x; r0v[2*i+1] = p0.y;
            r1v[2*i] = p1.x; r1v[2*i+1] = p1.y;
            r2v[2*i] = p2.x; r2v[2*i+1] = p2.y;
        }
        #pragma unroll
        for (int oc = 0; oc < 3; oc++){
            int wb = (oc*64 + ol)*122 + c*10;       // ushort index, even
            unsigned pa = wu32[wb>>1], pb = wu32[(wb>>1)+1];
            unsigned pc = wu32[(wb>>1)+2], pd = wu32[(wb>>1)+3];
            float w0 = bflo(pa), w1 = bfhi(pa);
            float w2 = bflo(pb), w3 = bfhi(pb);
            float w4 = bflo(pc), w5 = bfhi(pc);
            float w6 = bflo(pd), w7 = bfhi(pd);
            float w8 = bflo((unsigned)wu[wb + 8]);
            #pragma unroll
            for (int p = 0; p < 6; p++){
                a0[oc][p] += w0*r0v[p] + w1*r0v[p+1] + w2*r0v[p+2]
                           + w3*r1v[p] + w4*r1v[p+1] + w5*r1v[p+2]
                           + w6*r2v[p] + w7*r2v[p+1] + w8*r2v[p+2];
            }
        }
    }

    #pragma unroll
    for (int oc = 0; oc < 3; oc++){
        float* ap = acc + ((long)(cs*NB + n)*PX + hh*WP + x0)*CO + obase + oc*64;
        #pragma unroll
        for (int p = 0; p < 6; p++) ap[p*CO] = a0[oc][p];
    }
}

// ---- ssm: sum partials -> conv1d tap + SiLU gates -> x_proj/dt/BC -> gate ->
//               out_proj + residual. block 256 = 4 waves = 4 pixels; grid NB*PX/4.
__global__ __launch_bounds__(256) void ssmproj_k(
    const float* __restrict__ acc,
    const float* __restrict__ c1w, const float* __restrict__ c1b,
    const float* __restrict__ xpw, const float* __restrict__ dtw,
    const float* __restrict__ dtb, const float* __restrict__ Dp,
    const float* __restrict__ wpT,
    const float* __restrict__ xres, long nStrR, long cStrR,
    float* __restrict__ dst)
{
    __shared__ float gl[4][CI];
    int wave = threadIdx.x >> 6, lane = threadIdx.x & 63;
    int p0 = blockIdx.x*4;
    int p  = p0 + wave;
    int n  = p / PX, px = p % PX;

    float xi[3], sz[3];
    #pragma unroll
    for (int t = 0; t < 3; t++){
        int c = lane + 64*t;
        float xr = 0.f, zr = 0.f;
        #pragma unroll
        for (int q = 0; q < CSPLIT; q++){
            const float* ap = acc + ((long)(q*NB + n)*PX + px)*CO;
            xr += ap[c]; zr += ap[CI + c];
        }
        xi[t] = siluf(xr*c1w[c*4 + 3] + c1b[c]);
        sz[t] = siluf(zr);
    }

    float dbc[NDBC];
    #pragma unroll
    for (int j = 0; j < NDBC; j++){
        float s = 0.f;
        #pragma unroll
        for (int t = 0; t < 3; t++) s += xi[t]*xpw[j*CI + lane + 64*t];
        dbc[j] = s;
    }
    #pragma unroll
    for (int step = 1; step < 64; step <<= 1){
        #pragma unroll
        for (int j = 0; j < NDBC; j++) dbc[j] += __shfl_xor(dbc[j], step, 64);
    }
    float BC = 0.f;
    #pragma unroll
    for (int s = 0; s < 16; s++) BC += dbc[6+s]*dbc[22+s];

    #pragma unroll
    for (int t = 0; t < 3; t++){
        int c = lane + 64*t;
        float dl = dtb[c];
        #pragma unroll
        for (int r = 0; r < DTR; r++) dl += dbc[r]*dtw[c*DTR + r];
        dl = softplusf(dl);
        gl[wave][c] = xi[t]*(dl*BC + Dp[c])*sz[t];
    }
    __syncthreads();

    for (int idx = threadIdx.x; idx < 4*CM; idx += 256){
        int pl = idx / CM, m = idx % CM;
        int pp = p0 + pl;
        int nn = pp / PX, ppx = pp % PX;
        const float* g = gl[pl];
        float s0 = 0.f, s1 = 0.f, s2 = 0.f, s3 = 0.f;
        for (int c = 0; c < CI; c += 4){
            s0 += g[c+0]*wpT[(c+0)*CM + m];
            s1 += g[c+1]*wpT[(c+1)*CM + m];
            s2 += g[c+2]*wpT[(c+2)*CM + m];
            s3 += g[c+3]*wpT[(c+3)*CM + m];
        }
        float s = (s0+s1) + (s2+s3);
        s += xres[(long)nn*nStrR + (long)m*cStrR + ppx];
        dst[(nn*CM + m)*PX + ppx] = s;
    }
}

extern "C" void kernel_launch(void* const* d_in, const int* in_sizes, int n_in,
                              void* d_out, int out_size, void* d_ws, size_t ws_size,
                              hipStream_t stream) {
    const float* x_in = (const float*)d_in[0];   // (2,96,8,24,24)
    const float* ipw  = (const float*)d_in[1];   // (2,384,96,1,3,3)
    const float* c1w  = (const float*)d_in[2];   // (2,192,1,4,1,1)
    const float* c1b  = (const float*)d_in[3];   // (2,192)
    const float* xpw  = (const float*)d_in[4];   // (2,38,192)
    const float* dtw  = (const float*)d_in[5];   // (2,192,6)
    const float* dtb  = (const float*)d_in[6];   // (2,192)
    // d_in[7] = A_log: unused at depth 0 (multiplies h[-1]=0)
    const float* Dp   = (const float*)d_in[8];   // (2,192)
    const float* opw  = (const float*)d_in[9];   // (2,96,192)
    const float* nw   = (const float*)d_in[10];  // (2,1,96,1,1,1)

    char* ws = (char*)d_ws;
    float* wpT = (float*)ws;                                // 2*18432 f = 147456 B
    float* acc = wpT + 2*WPT_L;                             // 8*2*576*384 f = 14155776 B
    float* x1  = acc + (long)CSPLIT*NB*PX*CO;               // 110592 f

    // ---- layer 0 (input: depth-0 slice of x, strides of (2,96,8,24,24));
    //      also produces wpT for both ssm dispatches.
    conv_k<<<dim3(NB*HP, 2, CSPLIT), 256, 0, stream>>>(
        x_in, 96L*8*PX, 8L*PX, nw, ipw, acc, opw, wpT);
    ssmproj_k<<<NB*PX/4, 256, 0, stream>>>(
        acc, c1w, c1b, xpw, dtw, dtb, Dp, wpT,
        x_in, 96L*8*PX, 8L*PX, x1);

    // ---- layer 1 (input x1 packed (2,96,24,24); writes final output)
    conv_k<<<dim3(NB*HP, 2, CSPLIT), 256, 0, stream>>>(
        x1, 96L*PX, (long)PX, nw + CM, ipw + IPW_L, acc, nullptr, nullptr);
    ssmproj_k<<<NB*PX/4, 256, 0, stream>>>(
        acc, c1w + CI*4, c1b + CI, xpw + NDBC*CI, dtw + CI*DTR, dtb + CI, Dp + CI, wpT + WPT_L,
        x1, 96L*PX, (long)PX, (float*)d_out);
}

// Round 8
// 169.474 us; speedup vs baseline: 1.1176x; 1.1176x over previous
//
#include <hip/hip_runtime.h>
#include <math.h>

// Depth collapses to d=0 (x[:, :, 0:1] slicing): conv1d -> w[3]*xi+b,
// scan at d=0 -> hs[0]=BX[0] (A_log unused), y = xi*(delta*sum(B*C)+D).
//
// Round-8: 4 dispatches (conv0, ssm0, conv1, ssm1), prep_k folded into conv:
//  - conv self-stages fp32 weights -> bf16 LDS per block, float4-coalesced
//    (13.5 float4/thread, 432B runs), same barrier phase as hs staging.
//  - og3 = 3 chunks of 128 outputs: weight LDS 31KB, total ~35.5KB ->
//    4 blocks/CU = 16 waves/CU (r7's 51KB/3-block config was the
//    regression: occupancy 26%). Grid (48,3,8) = 1152 blocks.
//  - LDS weight layout [o'][c][10] stride 122 ush (61 words, gcd(61,32)=1
//    -> 2-way bank access = free), verified in r7.
//  - wpT built by conv0's grid (32 elems/block), consumed by LATER ssm
//    dispatches (stream-ordered, no fences; r1/r5 lesson).
//  - ssmproj_k byte-identical to round-6 (154.5us best).
#define NB   2
#define CM   96      // D_MODEL
#define CI   192     // D_INNER
#define CO   384     // 2*D_INNER
#define HP   24
#define WP   24
#define PX   576
#define DTR  6
#define NDBC 38
#define CSPLIT 8
#define CCH  12      // input channels per conv chunk (96/CSPLIT)
#define IPW_L (CO*CM*9)   // 331776 floats per layer of in_proj
#define WPT_L (CI*CM)     // 18432

__device__ __forceinline__ float siluf(float x){ return x / (1.f + expf(-x)); }
__device__ __forceinline__ float softplusf(float x){ return x > 20.f ? x : log1pf(expf(x)); }
__device__ __forceinline__ unsigned short f2bf(float f){
    unsigned u = __float_as_uint(f);
    return (unsigned short)((u + 0x7fffu + ((u >> 16) & 1u)) >> 16);
}
__device__ __forceinline__ float bflo(unsigned u){ return __uint_as_float(u << 16); }
__device__ __forceinline__ float bfhi(unsigned u){ return __uint_as_float(u & 0xffff0000u); }

// ---- conv: fused rmsnorm + 3x3 conv (pad 1), self-staged bf16 weights,
// fp32 accum. grid (NB*HP, 3 og3, CSPLIT) = 1152 blocks, block 256
// (4 waves x 6-px strips). Each block computes 2 o-chunks of 64 (c outer,
// oc inner so hs LDS reads amortize 2x). acc layout: [cs][n][px][o]
__global__ __launch_bounds__(256) void conv_k(
    const float* __restrict__ x, long nStr, long cStr,
    const float* __restrict__ nw,
    const float* __restrict__ ipw,      // layer base: [o][c][9] fp32
    float* __restrict__ acc,
    const float* __restrict__ opw,      // full (2,96,192) or null
    float* __restrict__ wpT)            // full 2*WPT_L or null
{
    __shared__ unsigned short wu[128*122];  // bf16 taps [o'][c][10-pad] = 31232 B
    __shared__ float hs[CCH][3][28];        // every (c,j) row base 16B-aligned
    __shared__ float scl[CCH][3];
    int bx  = blockIdx.x;
    int og3 = blockIdx.y;              // 0..2 -> outputs og3*128 .. +128
    int cs  = blockIdx.z;
    int n  = bx / HP, hh = bx % HP;
    int tid = threadIdx.x;
    int c0 = cs*CCH;

    // ---- wpT prologue (conv0 only): 32 elements per block, consumed by
    // the LATER ssm dispatches (stream-ordered, no fence needed).
    if (wpT != nullptr && tid < 32){
        int lin = bx + (NB*HP)*(og3 + 3*cs);     // 0..1151
        int j = lin*32 + tid;                     // 0..36863 = 2*WPT_L
        int l = j / WPT_L, r = j - l*WPT_L;
        int c = r / CM, m = r - c*CM;
        wpT[l*WPT_L + c*CM + m] = opw[(long)(l*CM + m)*CI + c];
    }

    if (tid < CCH*3){
        int c = tid/3, j = tid%3;
        int row = hh + j - 1;
        float s = 0.f;
        if (row >= 0 && row < HP){
            const float4* xp4 = (const float4*)(x + (long)n*nStr + (long)(c0+c)*cStr + row*WP);
            #pragma unroll
            for (int w4 = 0; w4 < WP/4; w4++){
                float4 v = xp4[w4];
                s += v.x*v.x + v.y*v.y + v.z*v.z + v.w*v.w;
            }
            s = rsqrtf(s*(1.0f/WP) + 1e-5f) * nw[c0+c];
        }
        scl[c][j] = s;
    }
    __syncthreads();

    // ---- stage hs (normalized input halo rows)
    for (int idx = tid; idx < CCH*3*28; idx += 256){
        int c = idx/84; int rem = idx%84; int j = rem/28; int wc = rem%28;
        int row = hh + j - 1;
        float v = 0.f;
        if (row >= 0 && row < HP && wc >= 1 && wc <= WP)
            v = x[(long)n*nStr + (long)(c0+c)*cStr + row*WP + (wc-1)] * scl[c][j];
        hs[c][j][wc] = v;
    }

    // ---- stage weights: 128 outputs x 108 taps, float4-coalesced fp32
    // reads (432B runs), bf16 pack into [o'][c*10 + k] (stride 122 ush =
    // 61 words, gcd(61,32)=1 -> 2-way bank access = free).
    {
        const float4* wsrc4 = (const float4*)ipw + (long)og3*128*216 + cs*27;
        for (int li4 = tid; li4 < 128*27; li4 += 256){
            int o2 = li4 / 27, q = li4 - o2*27;
            float4 v = wsrc4[(long)o2*216 + q];
            int t0 = q*4;
            unsigned short* wrow = wu + o2*122;
            wrow[((t0  )/9)*10 + (t0  )%9] = f2bf(v.x);
            wrow[((t0+1)/9)*10 + (t0+1)%9] = f2bf(v.y);
            wrow[((t0+2)/9)*10 + (t0+2)%9] = f2bf(v.z);
            wrow[((t0+3)/9)*10 + (t0+3)%9] = f2bf(v.w);
        }
    }
    __syncthreads();

    int ol = tid & 63;
    int obase = og3*128 + ol;          // + oc*64, oc in 0..1
    int x0 = (tid >> 6) * 6;           // even -> 8B-aligned float2 loads
    float a0[2][6] = {{0,0,0,0,0,0},{0,0,0,0,0,0}};
    const unsigned* wu32 = (const unsigned*)wu;

    for (int c = 0; c < CCH; c++){
        float r0v[8], r1v[8], r2v[8];
        #pragma unroll
        for (int i = 0; i < 4; i++){
            float2 p0 = *(const float2*)(&hs[c][0][x0] + 2*i);
            float2 p1 = *(const float2*)(&hs[c][1][x0] + 2*i);
            float2 p2 = *(const float2*)(&hs[c][2][x0] + 2*i);
            r0v[2*i] = p0.x; r0v[2*i+1] = p0.y;
            r1v[2*i] = p1.x; r1v[2*i+1] = p1.y;
            r2v[2*i] = p2.x; r2v[2*i+1] = p2.y;
        }
        #pragma unroll
        for (int oc = 0; oc < 2; oc++){
            int wb = (oc*64 + ol)*122 + c*10;       // ushort index, even
            unsigned pa = wu32[wb>>1], pb = wu32[(wb>>1)+1];
            unsigned pc = wu32[(wb>>1)+2], pd = wu32[(wb>>1)+3];
            float w0 = bflo(pa), w1 = bfhi(pa);
            float w2 = bflo(pb), w3 = bfhi(pb);
            float w4 = bflo(pc), w5 = bfhi(pc);
            float w6 = bflo(pd), w7 = bfhi(pd);
            float w8 = bflo((unsigned)wu[wb + 8]);
            #pragma unroll
            for (int p = 0; p < 6; p++){
                a0[oc][p] += w0*r0v[p] + w1*r0v[p+1] + w2*r0v[p+2]
                           + w3*r1v[p] + w4*r1v[p+1] + w5*r1v[p+2]
                           + w6*r2v[p] + w7*r2v[p+1] + w8*r2v[p+2];
            }
        }
    }

    #pragma unroll
    for (int oc = 0; oc < 2; oc++){
        float* ap = acc + ((long)(cs*NB + n)*PX + hh*WP + x0)*CO + obase + oc*64;
        #pragma unroll
        for (int p = 0; p < 6; p++) ap[p*CO] = a0[oc][p];
    }
}

// ---- ssm: sum partials -> conv1d tap + SiLU gates -> x_proj/dt/BC -> gate ->
//               out_proj + residual. block 256 = 4 waves = 4 pixels; grid NB*PX/4.
__global__ __launch_bounds__(256) void ssmproj_k(
    const float* __restrict__ acc,
    const float* __restrict__ c1w, const float* __restrict__ c1b,
    const float* __restrict__ xpw, const float* __restrict__ dtw,
    const float* __restrict__ dtb, const float* __restrict__ Dp,
    const float* __restrict__ wpT,
    const float* __restrict__ xres, long nStrR, long cStrR,
    float* __restrict__ dst)
{
    __shared__ float gl[4][CI];
    int wave = threadIdx.x >> 6, lane = threadIdx.x & 63;
    int p0 = blockIdx.x*4;
    int p  = p0 + wave;
    int n  = p / PX, px = p % PX;

    float xi[3], sz[3];
    #pragma unroll
    for (int t = 0; t < 3; t++){
        int c = lane + 64*t;
        float xr = 0.f, zr = 0.f;
        #pragma unroll
        for (int q = 0; q < CSPLIT; q++){
            const float* ap = acc + ((long)(q*NB + n)*PX + px)*CO;
            xr += ap[c]; zr += ap[CI + c];
        }
        xi[t] = siluf(xr*c1w[c*4 + 3] + c1b[c]);
        sz[t] = siluf(zr);
    }

    float dbc[NDBC];
    #pragma unroll
    for (int j = 0; j < NDBC; j++){
        float s = 0.f;
        #pragma unroll
        for (int t = 0; t < 3; t++) s += xi[t]*xpw[j*CI + lane + 64*t];
        dbc[j] = s;
    }
    #pragma unroll
    for (int step = 1; step < 64; step <<= 1){
        #pragma unroll
        for (int j = 0; j < NDBC; j++) dbc[j] += __shfl_xor(dbc[j], step, 64);
    }
    float BC = 0.f;
    #pragma unroll
    for (int s = 0; s < 16; s++) BC += dbc[6+s]*dbc[22+s];

    #pragma unroll
    for (int t = 0; t < 3; t++){
        int c = lane + 64*t;
        float dl = dtb[c];
        #pragma unroll
        for (int r = 0; r < DTR; r++) dl += dbc[r]*dtw[c*DTR + r];
        dl = softplusf(dl);
        gl[wave][c] = xi[t]*(dl*BC + Dp[c])*sz[t];
    }
    __syncthreads();

    for (int idx = threadIdx.x; idx < 4*CM; idx += 256){
        int pl = idx / CM, m = idx % CM;
        int pp = p0 + pl;
        int nn = pp / PX, ppx = pp % PX;
        const float* g = gl[pl];
        float s0 = 0.f, s1 = 0.f, s2 = 0.f, s3 = 0.f;
        for (int c = 0; c < CI; c += 4){
            s0 += g[c+0]*wpT[(c+0)*CM + m];
            s1 += g[c+1]*wpT[(c+1)*CM + m];
            s2 += g[c+2]*wpT[(c+2)*CM + m];
            s3 += g[c+3]*wpT[(c+3)*CM + m];
        }
        float s = (s0+s1) + (s2+s3);
        s += xres[(long)nn*nStrR + (long)m*cStrR + ppx];
        dst[(nn*CM + m)*PX + ppx] = s;
    }
}

extern "C" void kernel_launch(void* const* d_in, const int* in_sizes, int n_in,
                              void* d_out, int out_size, void* d_ws, size_t ws_size,
                              hipStream_t stream) {
    const float* x_in = (const float*)d_in[0];   // (2,96,8,24,24)
    const float* ipw  = (const float*)d_in[1];   // (2,384,96,1,3,3)
    const float* c1w  = (const float*)d_in[2];   // (2,192,1,4,1,1)
    const float* c1b  = (const float*)d_in[3];   // (2,192)
    const float* xpw  = (const float*)d_in[4];   // (2,38,192)
    const float* dtw  = (const float*)d_in[5];   // (2,192,6)
    const float* dtb  = (const float*)d_in[6];   // (2,192)
    // d_in[7] = A_log: unused at depth 0 (multiplies h[-1]=0)
    const float* Dp   = (const float*)d_in[8];   // (2,192)
    const float* opw  = (const float*)d_in[9];   // (2,96,192)
    const float* nw   = (const float*)d_in[10];  // (2,1,96,1,1,1)

    char* ws = (char*)d_ws;
    float* wpT = (float*)ws;                                // 2*18432 f = 147456 B
    float* acc = wpT + 2*WPT_L;                             // 8*2*576*384 f = 14155776 B
    float* x1  = acc + (long)CSPLIT*NB*PX*CO;               // 110592 f

    // ---- layer 0 (input: depth-0 slice of x, strides of (2,96,8,24,24));
    //      also produces wpT for both ssm dispatches.
    conv_k<<<dim3(NB*HP, 3, CSPLIT), 256, 0, stream>>>(
        x_in, 96L*8*PX, 8L*PX, nw, ipw, acc, opw, wpT);
    ssmproj_k<<<NB*PX/4, 256, 0, stream>>>(
        acc, c1w, c1b, xpw, dtw, dtb, Dp, wpT,
        x_in, 96L*8*PX, 8L*PX, x1);

    // ---- layer 1 (input x1 packed (2,96,24,24); writes final output)
    conv_k<<<dim3(NB*HP, 3, CSPLIT), 256, 0, stream>>>(
        x1, 96L*PX, (long)PX, nw + CM, ipw + IPW_L, acc, nullptr, nullptr);
    ssmproj_k<<<NB*PX/4, 256, 0, stream>>>(
        acc, c1w + CI*4, c1b + CI, xpw + NDBC*CI, dtw + CI*DTR, dtb + CI, Dp + CI, wpT + WPT_L,
        x1, 96L*PX, (long)PX, (float*)d_out);
}

// Round 9
// 151.912 us; speedup vs baseline: 1.2468x; 1.1156x over previous
//
#include <hip/hip_runtime.h>
#include <math.h>

// Depth collapses to d=0 (x[:, :, 0:1] slicing): conv1d -> w[3]*xi+b,
// scan at d=0 -> hs[0]=BX[0] (A_log unused), y = xi*(delta*sum(B*C)+D).
//
// Round-9: exact r6 structure (5 dispatches: prep, conv0, ssm0, conv1,
// ssm1; 154.5us verified) + software-pipelined conv c-loop:
//  - c+1's weights (3x uint4 + 3x u16) and hs rows (12x float2) are
//    loaded while c's FMA burst executes (conv was measured
//    latency-bound: r7 profile Occ 26%/VALUBusy 30%).
//  - __launch_bounds__(256,3) matches grid-limited 3 blocks/CU so the
//    extra ~50 prefetch VGPRs don't cost occupancy.
// Dispatch count pinned at 5: r3/r7/r8 all showed prep-removal costs
// more than the launch slot saves. No cross-block dataflow (r1/r5).
#define NB   2
#define CM   96      // D_MODEL
#define CI   192     // D_INNER
#define CO   384     // 2*D_INNER
#define HP   24
#define WP   24
#define PX   576
#define DTR  6
#define NDBC 38
#define CSPLIT 8
#define CCH  12      // input channels per conv chunk (96/CSPLIT)

__device__ __forceinline__ float siluf(float x){ return x / (1.f + expf(-x)); }
__device__ __forceinline__ float softplusf(float x){ return x > 20.f ? x : log1pf(expf(x)); }
__device__ __forceinline__ unsigned short f2bf(float f){
    unsigned u = __float_as_uint(f);
    return (unsigned short)((u + 0x7fffu + ((u >> 16) & 1u)) >> 16);
}
__device__ __forceinline__ float bflo(unsigned u){ return __uint_as_float(u << 16); }
__device__ __forceinline__ float bfhi(unsigned u){ return __uint_as_float(u & 0xffff0000u); }

// ---- prep: pack in_proj weights to bf16: wQb[l][c][o][k0..7] (ushort8 = uint4)
//            + wRb[l][c][o] (tap 8), and transpose out_proj -> wpT[l][c][m] fp32
#define NW_IN (2*CO*CM*9)      // 663552
#define WQB_L (CM*CO*8)        // ushorts per layer
#define WRB_L (CM*CO)
#define WPT_L (CI*CM)
__global__ void prep_k(const float* __restrict__ ipw, const float* __restrict__ opw,
                       unsigned short* __restrict__ wQb, unsigned short* __restrict__ wRb,
                       float* __restrict__ wpT){
    int idx = blockIdx.x*256 + threadIdx.x;
    if (idx < NW_IN){
        int l = idx / (CO*CM*9);
        int r = idx % (CO*CM*9);
        int o = r / (CM*9);
        int r2 = r % (CM*9);
        int c = r2 / 9;
        int k = r2 % 9;
        unsigned short v = f2bf(ipw[idx]);
        if (k < 8) wQb[(long)l*WQB_L + ((c*CO + o)<<3) + k] = v;
        else       wRb[(long)l*WRB_L + c*CO + o] = v;
    } else {
        int j = idx - NW_IN;
        if (j < 2*CI*CM){
            int l = j / (CI*CM);
            int r = j % (CI*CM);
            int c = r / CM;
            int m = r % CM;
            wpT[l*WPT_L + c*CM + m] = opw[(l*CM + m)*CI + c];
        }
    }
}

// ---- conv: fused rmsnorm + 3x3 conv (pad 1), bf16 weights, fp32 accum.
// grid (NB*HP, 2 og2-halves, CSPLIT c-chunks) = 768 blocks, block 256
// (4 waves x 6-px strips). Each block computes 3 o-chunks of 64 outputs;
// c-loop outermost, double-buffered: c+1 weight/hs loads issued before
// c's FMA burst. acc layout: [cs][n][px][o]
__global__ __launch_bounds__(256, 3) void conv_k(
    const float* __restrict__ x, long nStr, long cStr,
    const float* __restrict__ nw,
    const unsigned short* __restrict__ wQb, const unsigned short* __restrict__ wRb,
    float* __restrict__ acc)
{
    __shared__ float hs[CCH][3][28];   // 28-wide rows: every (c,j) row base 16B-aligned
    __shared__ float scl[CCH][3];
    int bx  = blockIdx.x;
    int og2 = blockIdx.y;              // 0..1 -> outputs og2*192 .. +192
    int cs  = blockIdx.z;
    int n  = bx / HP, hh = bx % HP;
    int tid = threadIdx.x;
    int c0 = cs*CCH;

    if (tid < CCH*3){
        int c = tid/3, j = tid%3;
        int row = hh + j - 1;
        float s = 0.f;
        if (row >= 0 && row < HP){
            const float4* xp4 = (const float4*)(x + (long)n*nStr + (long)(c0+c)*cStr + row*WP);
            #pragma unroll
            for (int w4 = 0; w4 < WP/4; w4++){
                float4 v = xp4[w4];
                s += v.x*v.x + v.y*v.y + v.z*v.z + v.w*v.w;
            }
            s = rsqrtf(s*(1.0f/WP) + 1e-5f) * nw[c0+c];
        }
        scl[c][j] = s;
    }
    __syncthreads();

    for (int idx = tid; idx < CCH*3*28; idx += 256){
        int c = idx/84; int rem = idx%84; int j = rem/28; int wc = rem%28;
        int row = hh + j - 1;
        float v = 0.f;
        if (row >= 0 && row < HP && wc >= 1 && wc <= WP)
            v = x[(long)n*nStr + (long)(c0+c)*cStr + row*WP + (wc-1)] * scl[c][j];
        hs[c][j][wc] = v;
    }
    __syncthreads();

    int ol = tid & 63;
    int obase = og2*192 + ol;          // + oc*64, oc in 0..2
    int x0 = (tid >> 6) * 6;           // even -> 8B-aligned float2 loads
    float a0[3][6] = {{0,0,0,0,0,0},{0,0,0,0,0,0},{0,0,0,0,0,0}};
    const uint4* wq4 = (const uint4*)wQb;

    // ---- software pipeline: prefetch c=0
    uint4 nw4[3]; unsigned short nw8[3];
    float2 nh[3][4];
    {
        int cg = c0;
        #pragma unroll
        for (int oc = 0; oc < 3; oc++){
            nw4[oc] = wq4[cg*CO + obase + oc*64];
            nw8[oc] = wRb[cg*CO + obase + oc*64];
        }
        #pragma unroll
        for (int j = 0; j < 3; j++)
            #pragma unroll
            for (int i = 0; i < 4; i++)
                nh[j][i] = *(const float2*)(&hs[0][j][x0] + 2*i);
    }

    for (int c = 0; c < CCH; c++){
        // rotate prefetched -> current
        uint4 cw4[3]; unsigned short cw8[3]; float2 ch[3][4];
        #pragma unroll
        for (int oc = 0; oc < 3; oc++){ cw4[oc] = nw4[oc]; cw8[oc] = nw8[oc]; }
        #pragma unroll
        for (int j = 0; j < 3; j++)
            #pragma unroll
            for (int i = 0; i < 4; i++) ch[j][i] = nh[j][i];

        // issue c+1 loads (hidden under this c's FMA burst)
        if (c + 1 < CCH){
            int cg = c0 + c + 1;
            #pragma unroll
            for (int oc = 0; oc < 3; oc++){
                nw4[oc] = wq4[cg*CO + obase + oc*64];
                nw8[oc] = wRb[cg*CO + obase + oc*64];
            }
            #pragma unroll
            for (int j = 0; j < 3; j++)
                #pragma unroll
                for (int i = 0; i < 4; i++)
                    nh[j][i] = *(const float2*)(&hs[c+1][j][x0] + 2*i);
        }

        float r0v[8], r1v[8], r2v[8];
        #pragma unroll
        for (int i = 0; i < 4; i++){
            r0v[2*i] = ch[0][i].x; r0v[2*i+1] = ch[0][i].y;
            r1v[2*i] = ch[1][i].x; r1v[2*i+1] = ch[1][i].y;
            r2v[2*i] = ch[2][i].x; r2v[2*i+1] = ch[2][i].y;
        }
        #pragma unroll
        for (int oc = 0; oc < 3; oc++){
            uint4 wv = cw4[oc];
            float w0 = bflo(wv.x), w1 = bfhi(wv.x);
            float w2 = bflo(wv.y), w3 = bfhi(wv.y);
            float w4 = bflo(wv.z), w5 = bfhi(wv.z);
            float w6 = bflo(wv.w), w7 = bfhi(wv.w);
            float w8 = bflo((unsigned)cw8[oc]);
            #pragma unroll
            for (int p = 0; p < 6; p++){
                a0[oc][p] += w0*r0v[p] + w1*r0v[p+1] + w2*r0v[p+2]
                           + w3*r1v[p] + w4*r1v[p+1] + w5*r1v[p+2]
                           + w6*r2v[p] + w7*r2v[p+1] + w8*r2v[p+2];
            }
        }
    }

    #pragma unroll
    for (int oc = 0; oc < 3; oc++){
        float* ap = acc + ((long)(cs*NB + n)*PX + hh*WP + x0)*CO + obase + oc*64;
        #pragma unroll
        for (int p = 0; p < 6; p++) ap[p*CO] = a0[oc][p];
    }
}

// ---- ssm: sum partials -> conv1d tap + SiLU gates -> x_proj/dt/BC -> gate ->
//               out_proj + residual. block 256 = 4 waves = 4 pixels; grid NB*PX/4.
__global__ __launch_bounds__(256) void ssmproj_k(
    const float* __restrict__ acc,
    const float* __restrict__ c1w, const float* __restrict__ c1b,
    const float* __restrict__ xpw, const float* __restrict__ dtw,
    const float* __restrict__ dtb, const float* __restrict__ Dp,
    const float* __restrict__ wpT,
    const float* __restrict__ xres, long nStrR, long cStrR,
    float* __restrict__ dst)
{
    __shared__ float gl[4][CI];
    int wave = threadIdx.x >> 6, lane = threadIdx.x & 63;
    int p0 = blockIdx.x*4;
    int p  = p0 + wave;
    int n  = p / PX, px = p % PX;

    float xi[3], sz[3];
    #pragma unroll
    for (int t = 0; t < 3; t++){
        int c = lane + 64*t;
        float xr = 0.f, zr = 0.f;
        #pragma unroll
        for (int q = 0; q < CSPLIT; q++){
            const float* ap = acc + ((long)(q*NB + n)*PX + px)*CO;
            xr += ap[c]; zr += ap[CI + c];
        }
        xi[t] = siluf(xr*c1w[c*4 + 3] + c1b[c]);
        sz[t] = siluf(zr);
    }

    float dbc[NDBC];
    #pragma unroll
    for (int j = 0; j < NDBC; j++){
        float s = 0.f;
        #pragma unroll
        for (int t = 0; t < 3; t++) s += xi[t]*xpw[j*CI + lane + 64*t];
        dbc[j] = s;
    }
    #pragma unroll
    for (int step = 1; step < 64; step <<= 1){
        #pragma unroll
        for (int j = 0; j < NDBC; j++) dbc[j] += __shfl_xor(dbc[j], step, 64);
    }
    float BC = 0.f;
    #pragma unroll
    for (int s = 0; s < 16; s++) BC += dbc[6+s]*dbc[22+s];

    #pragma unroll
    for (int t = 0; t < 3; t++){
        int c = lane + 64*t;
        float dl = dtb[c];
        #pragma unroll
        for (int r = 0; r < DTR; r++) dl += dbc[r]*dtw[c*DTR + r];
        dl = softplusf(dl);
        gl[wave][c] = xi[t]*(dl*BC + Dp[c])*sz[t];
    }
    __syncthreads();

    for (int idx = threadIdx.x; idx < 4*CM; idx += 256){
        int pl = idx / CM, m = idx % CM;
        int pp = p0 + pl;
        int nn = pp / PX, ppx = pp % PX;
        const float* g = gl[pl];
        float s0 = 0.f, s1 = 0.f, s2 = 0.f, s3 = 0.f;
        for (int c = 0; c < CI; c += 4){
            s0 += g[c+0]*wpT[(c+0)*CM + m];
            s1 += g[c+1]*wpT[(c+1)*CM + m];
            s2 += g[c+2]*wpT[(c+2)*CM + m];
            s3 += g[c+3]*wpT[(c+3)*CM + m];
        }
        float s = (s0+s1) + (s2+s3);
        s += xres[(long)nn*nStrR + (long)m*cStrR + ppx];
        dst[(nn*CM + m)*PX + ppx] = s;
    }
}

extern "C" void kernel_launch(void* const* d_in, const int* in_sizes, int n_in,
                              void* d_out, int out_size, void* d_ws, size_t ws_size,
                              hipStream_t stream) {
    const float* x_in = (const float*)d_in[0];   // (2,96,8,24,24)
    const float* ipw  = (const float*)d_in[1];   // (2,384,96,1,3,3)
    const float* c1w  = (const float*)d_in[2];   // (2,192,1,4,1,1)
    const float* c1b  = (const float*)d_in[3];   // (2,192)
    const float* xpw  = (const float*)d_in[4];   // (2,38,192)
    const float* dtw  = (const float*)d_in[5];   // (2,192,6)
    const float* dtb  = (const float*)d_in[6];   // (2,192)
    // d_in[7] = A_log: unused at depth 0 (multiplies h[-1]=0)
    const float* Dp   = (const float*)d_in[8];   // (2,192)
    const float* opw  = (const float*)d_in[9];   // (2,96,192)
    const float* nw   = (const float*)d_in[10];  // (2,1,96,1,1,1)

    char* ws = (char*)d_ws;
    unsigned short* wQb = (unsigned short*)ws;              // 2*294912 ush = 1179648 B
    unsigned short* wRb = wQb + 2*WQB_L;                    // 2*36864 ush  = 147456 B
    float* wpT = (float*)(wRb + 2*WRB_L);                   // 2*18432 f    = 147456 B
    float* acc = wpT + 2*WPT_L;                             // 8*2*576*384 f = 14155776 B
    float* x1  = acc + (long)CSPLIT*NB*PX*CO;               // 110592 f

    prep_k<<<(NW_IN + 2*CI*CM + 255)/256, 256, 0, stream>>>(ipw, opw, wQb, wRb, wpT);

    // ---- layer 0 (input: depth-0 slice of x, strides of (2,96,8,24,24))
    conv_k<<<dim3(NB*HP, 2, CSPLIT), 256, 0, stream>>>(
        x_in, 96L*8*PX, 8L*PX, nw, wQb, wRb, acc);
    ssmproj_k<<<NB*PX/4, 256, 0, stream>>>(
        acc, c1w, c1b, xpw, dtw, dtb, Dp, wpT,
        x_in, 96L*8*PX, 8L*PX, x1);

    // ---- layer 1 (input x1 packed (2,96,24,24); writes final output)
    conv_k<<<dim3(NB*HP, 2, CSPLIT), 256, 0, stream>>>(
        x1, 96L*PX, (long)PX, nw + CM, wQb + WQB_L, wRb + WRB_L, acc);
    ssmproj_k<<<NB*PX/4, 256, 0, stream>>>(
        acc, c1w + CI*4, c1b + CI, xpw + NDBC*CI, dtw + CI*DTR, dtb + CI, Dp + CI, wpT + WPT_L,
        x1, 96L*PX, (long)PX, (float*)d_out);
}